// Round 1
// baseline (366.764 us; speedup 1.0000x reference)
//
#include <hip/hip_runtime.h>

// Quantizer: nearest-codebook lookup.
//   x: [16, 64, 32, 32] fp32 (NCHW), embed: [64, 8192] fp32
//   out: [16, 32, 32, 64] fp32 = embed[:, argmin_j ||flat_n - e_j||²]^T gathered
//
// argmin_j (||f||² - 2 f·e_j + ||e_j||²) == argmin_j (||e_j||² - 2 f·e_j)
// so we fuse a 16384x8192x64 fp32 GEMM with a running per-row argmin.

#define N_ROWS 16384   // 16*32*32
#define E_DIM  64
#define N_EMBED 8192
#define BN 128         // rows per block
#define BJ 128         // codes per j-tile
#define NCHUNK 4       // j-range split across blocks (partial argmin + 2nd pass)
#define JCHUNK (N_EMBED / NCHUNK)   // 2048

// ---- phase 0a: transpose embed [64][8192] -> embedT [8192][64] (for the gather)
__global__ void transpose_embed(const float* __restrict__ embed,
                                float* __restrict__ embedT) {
    __shared__ float tile[32][33];
    int j0 = blockIdx.x * 32;
    int c0 = blockIdx.y * 32;
    int tx = threadIdx.x, ty = threadIdx.y;
    tile[ty][tx] = embed[(c0 + ty) * N_EMBED + j0 + tx];
    __syncthreads();
    embedT[(j0 + ty) * E_DIM + c0 + tx] = tile[tx][ty];
}

// ---- phase 0b: ||e_j||² per code (coalesced across j)
__global__ void compute_enorm(const float* __restrict__ embed,
                              float* __restrict__ enorm) {
    int j = blockIdx.x * 256 + threadIdx.x;
    float s = 0.f;
#pragma unroll
    for (int c = 0; c < E_DIM; ++c) {
        float v = embed[c * N_EMBED + j];
        s = fmaf(v, v, s);
    }
    enorm[j] = s;
}

// ---- phase 1: fused GEMM + argmin over a JCHUNK of codes
// block: 256 thr; tile BN=128 rows x BJ=128 codes; per-thread 8x8 accs.
// LDS: A [64][128] fp32 (32KB) + B [64][128] fp32 (32KB) = 64KB -> 2 blocks/CU.
__global__ __launch_bounds__(256, 2) void qdist(
        const float* __restrict__ x, const float* __restrict__ embed,
        const float* __restrict__ enorm,
        float* __restrict__ pd, int* __restrict__ pi) {
    __shared__ float lds[16384];          // 64 KB exactly
    float* Alds = lds;                    // [c][row]  c<64, row<128
    float* Blds = lds + E_DIM * BN;       // [c][code] c<64, code<128

    const int t  = threadIdx.x;
    const int rb = blockIdx.x >> 2;       // 128 row-blocks
    const int jc = blockIdx.x & 3;        // 4 code-chunks
    const int n0 = rb * BN;
    const int b  = n0 >> 10;              // image index (1024 pixels each)
    const int p0 = n0 & 1023;
    const float* xb = x + b * (E_DIM * 1024) + p0;

    // stage A: A[c][i] = x[b][c][p0+i] — coalesced float4 runs per c
#pragma unroll
    for (int k = 0; k < 8; ++k) {
        int l4 = t + k * 256;             // 2048 float4 total
        int c  = l4 >> 5;                 // 32 float4 per c-row
        int i4 = (l4 & 31) << 2;
        *(float4*)(Alds + c * BN + i4) = *(const float4*)(xb + c * 1024 + i4);
    }

    const int jt = t & 15;                // 16 code-groups (8 codes each: jt*4 and 64+jt*4)
    const int rt = t >> 4;                // 16 row-groups (8 rows each)

    float best[8];
    int   bidx[8];
#pragma unroll
    for (int r = 0; r < 8; ++r) { best[r] = 3.4e38f; bidx[r] = 0x7fffffff; }

    const int j0base = jc * JCHUNK;
    for (int jtile = 0; jtile < JCHUNK; jtile += BJ) {
        const int j0 = j0base + jtile;
        __syncthreads();
        // stage B: B[c][jj] = embed[c][j0+jj] — coalesced float4
#pragma unroll
        for (int k = 0; k < 8; ++k) {
            int l4 = t + k * 256;
            int c  = l4 >> 5;
            int j4 = (l4 & 31) << 2;
            *(float4*)(Blds + c * BJ + j4) =
                *(const float4*)(embed + c * N_EMBED + j0 + j4);
        }
        __syncthreads();

        float acc[8][8];
#pragma unroll
        for (int r = 0; r < 8; ++r)
#pragma unroll
            for (int q = 0; q < 8; ++q) acc[r][q] = 0.f;

#pragma unroll 4
        for (int c = 0; c < E_DIM; ++c) {
            float4 a0 = *(float4*)(Alds + c * BN + rt * 8);
            float4 a1 = *(float4*)(Alds + c * BN + rt * 8 + 4);
            float4 b0 = *(float4*)(Blds + c * BJ + jt * 4);
            float4 b1 = *(float4*)(Blds + c * BJ + 64 + jt * 4);
            float av[8] = {a0.x, a0.y, a0.z, a0.w, a1.x, a1.y, a1.z, a1.w};
            float bv[8] = {b0.x, b0.y, b0.z, b0.w, b1.x, b1.y, b1.z, b1.w};
#pragma unroll
            for (int r = 0; r < 8; ++r)
#pragma unroll
                for (int q = 0; q < 8; ++q)
                    acc[r][q] = fmaf(av[r], bv[q], acc[r][q]);
        }

        // epilogue: dist = ||e||² - 2·dot ; running argmin (ascending j, strict <
        // keeps first occurrence = jnp.argmax(-d) tie semantics)
#pragma unroll
        for (int q = 0; q < 8; ++q) {
            int jl = (q < 4) ? (jt * 4 + q) : (64 + jt * 4 + (q - 4));
            int jg = j0 + jl;
            float e = enorm[jg];
#pragma unroll
            for (int r = 0; r < 8; ++r) {
                float d = fmaf(-2.f, acc[r][q], e);
                if (d < best[r]) { best[r] = d; bidx[r] = jg; }
            }
        }
    }

    // cross-thread (over jt groups) argmin reduction via LDS (A region reused)
    __syncthreads();
    float* rd = lds;                  // [128][16] floats = 8KB
    int*   ri = (int*)(lds + 2048);   // [128][16] ints   = 8KB
#pragma unroll
    for (int r = 0; r < 8; ++r) {
        int row = rt * 8 + r;
        rd[row * 16 + jt] = best[r];
        ri[row * 16 + jt] = bidx[r];
    }
    __syncthreads();
    if (t < BN) {
        float bd = rd[t * 16];
        int   bi = ri[t * 16];
#pragma unroll
        for (int k = 1; k < 16; ++k) {
            float d  = rd[t * 16 + k];
            int   i2 = ri[t * 16 + k];
            if (d < bd || (d == bd && i2 < bi)) { bd = d; bi = i2; }
        }
        int rowg = n0 + t;
        pd[rowg * NCHUNK + jc] = bd;
        pi[rowg * NCHUNK + jc] = bi;
    }
}

// ---- phase 2: reduce the NCHUNK partials per row, gather the winning code
__global__ void gather_out(const float* __restrict__ pd, const int* __restrict__ pi,
                           const float* __restrict__ embedT, float* __restrict__ out) {
    int t   = blockIdx.x * 256 + threadIdx.x;
    int row = t >> 6;
    int c   = t & 63;
    float bd = pd[row * NCHUNK];
    int   bi = pi[row * NCHUNK];
#pragma unroll
    for (int k = 1; k < NCHUNK; ++k) {
        float d  = pd[row * NCHUNK + k];
        int   i2 = pi[row * NCHUNK + k];
        if (d < bd || (d == bd && i2 < bi)) { bd = d; bi = i2; }
    }
    out[row * E_DIM + c] = embedT[bi * E_DIM + c];
}

extern "C" void kernel_launch(void* const* d_in, const int* in_sizes, int n_in,
                              void* d_out, int out_size, void* d_ws, size_t ws_size,
                              hipStream_t stream) {
    const float* x     = (const float*)d_in[0];
    const float* embed = (const float*)d_in[1];
    float* out = (float*)d_out;

    char* ws = (char*)d_ws;
    float* embedT = (float*)ws;                                        // 2 MB
    float* enorm  = (float*)(ws + (2u << 20));                         // 32 KB
    float* pd     = (float*)(ws + (2u << 20) + (32u << 10));           // 256 KB
    int*   pi     = (int*)  (ws + (2u << 20) + (32u << 10) + (256u << 10)); // 256 KB

    transpose_embed<<<dim3(N_EMBED / 32, E_DIM / 32), dim3(32, 32), 0, stream>>>(embed, embedT);
    compute_enorm<<<N_EMBED / 256, 256, 0, stream>>>(embed, enorm);
    qdist<<<(N_ROWS / BN) * NCHUNK, 256, 0, stream>>>(x, embed, enorm, pd, pi);
    gather_out<<<(N_ROWS * E_DIM) / 256, 256, 0, stream>>>(pd, pi, embedT, out);
}

// Round 2
// 307.064 us; speedup vs baseline: 1.1944x; 1.1944x over previous
//
#include <hip/hip_runtime.h>

// Quantizer: nearest-codebook lookup, fused fp32 GEMM + argmin.
//   x: [16, 64, 32, 32] fp32 (NCHW), embed: [64, 8192] fp32
//   out: [16, 32, 32, 64] fp32 = embedT[argmin_j ||flat_n - e_j||^2]
//
// argmin_j (||f||^2 - 2 f.e_j + ||e_j||^2) == argmax_j (f.e_j - ||e_j||^2/2)
//
// R2 design: A rows live in VGPRs (2 rows x 64 c per thread), B row embedT[j][:]
// is wave-uniform -> scalar loads (SGPRs). No LDS in the hot loop at all.
// Cross-chunk argmin via u64 atomicMax on (sortable-f32-key | ~idx).

#define E_DIM   64
#define N_EMBED 8192
#define N_ROWS  16384          // 16*32*32
#define NCHUNK  16             // code-range chunks (blocks racing via atomicMax)
#define JCHUNK  (N_EMBED / NCHUNK)   // 512
#define RB_ROWS 512            // rows per block (256 thr x 2 rows)
#define NRB     (N_ROWS / RB_ROWS)   // 32

// ---- phase 0a: transpose embed [64][8192] -> embedT [8192][64]
__global__ void transpose_embed(const float* __restrict__ embed,
                                float* __restrict__ embedT) {
    __shared__ float tile[32][33];
    int j0 = blockIdx.x * 32;
    int c0 = blockIdx.y * 32;
    int tx = threadIdx.x, ty = threadIdx.y;
    tile[ty][tx] = embed[(c0 + ty) * N_EMBED + j0 + tx];
    __syncthreads();
    embedT[(j0 + ty) * E_DIM + c0 + tx] = tile[tx][ty];
}

// ---- phase 0b: ||e_j||^2 per code (coalesced across j)
__global__ void compute_enorm(const float* __restrict__ embed,
                              float* __restrict__ enorm) {
    int j = blockIdx.x * 256 + threadIdx.x;
    float s = 0.f;
#pragma unroll
    for (int c = 0; c < E_DIM; ++c) {
        float v = embed[c * N_EMBED + j];
        s = fmaf(v, v, s);
    }
    enorm[j] = s;
}

// ---- phase 0c: zero the per-row key array (harness poisons ws with 0xAA)
__global__ void init_keys(unsigned long long* __restrict__ fkey) {
    fkey[blockIdx.x * 256 + threadIdx.x] = 0ull;
}

// monotone f32 -> u32 map (finite floats; larger float => larger uint)
__device__ __forceinline__ unsigned int f32_key(float s) {
    unsigned int u = __float_as_uint(s);
    return (u & 0x80000000u) ? ~u : (u | 0x80000000u);
}

// ---- phase 1: fused dot + argmax(score) over one JCHUNK of codes
// grid: 32 row-blocks x 16 chunks = 512 blocks; 256 thr; 2 rows/thread.
__global__ __launch_bounds__(256, 2) void qdist(
        const float* __restrict__ x, const float* __restrict__ embedT,
        const float* __restrict__ enorm,
        unsigned long long* __restrict__ fkey) {
    const int t  = threadIdx.x;
    const int rb = blockIdx.x >> 4;       // 32 row-blocks of 512 rows
    const int jc = blockIdx.x & 15;       // 16 code chunks of 512 codes
    const int n0 = rb * RB_ROWS;
    // rows n0..n0+511 are inside one image (512 | 1024)
    const float* xb = x + (n0 >> 10) * (E_DIM * 1024) + (n0 & 1023);

    // A fragment: rows (n0 + t) and (n0 + t + 256), all 64 channels, in VGPRs.
    float areg[128];
#pragma unroll
    for (int c = 0; c < E_DIM; ++c) {
        areg[c]      = xb[c * 1024 + t];        // coalesced across lanes
        areg[c + 64] = xb[c * 1024 + t + 256];
    }

    float bs0 = -3.4e38f, bs1 = -3.4e38f;
    int   bi0 = 0,        bi1 = 0;
    const int j0 = jc * JCHUNK;

    for (int jj = 0; jj < JCHUNK; ++jj) {
        const int j = j0 + jj;
        const float* bp = embedT + (j << 6);   // wave-uniform -> s_load
        float p00 = 0.f, p01 = 0.f, p10 = 0.f, p11 = 0.f;
#pragma unroll
        for (int c = 0; c < 32; ++c) {
            float b0 = bp[c];
            float b1 = bp[c + 32];
            p00 = fmaf(areg[c],      b0, p00);
            p01 = fmaf(areg[c + 32], b1, p01);
            p10 = fmaf(areg[c + 64], b0, p10);
            p11 = fmaf(areg[c + 96], b1, p11);
        }
        const float e  = 0.5f * enorm[j];       // uniform scalar
        const float s0 = (p00 + p01) - e;
        const float s1 = (p10 + p11) - e;
        // ascending j + strict > keeps first occurrence (argmax(-d) tie rule)
        if (s0 > bs0) { bs0 = s0; bi0 = j; }
        if (s1 > bs1) { bs1 = s1; bi1 = j; }
    }

    // pack: high 32 = sortable score (max wins), low 32 = ~idx (tie -> min idx)
    unsigned long long k0 =
        ((unsigned long long)f32_key(bs0) << 32) | (unsigned int)(~(unsigned int)bi0);
    unsigned long long k1 =
        ((unsigned long long)f32_key(bs1) << 32) | (unsigned int)(~(unsigned int)bi1);
    atomicMax(&fkey[n0 + t],       k0);
    atomicMax(&fkey[n0 + t + 256], k1);
}

// ---- phase 2: decode winning index, gather the code row
__global__ void gather_out(const unsigned long long* __restrict__ fkey,
                           const float* __restrict__ embedT,
                           float* __restrict__ out) {
    int t   = blockIdx.x * 256 + threadIdx.x;
    int row = t >> 6;
    int c   = t & 63;
    int idx = (int)(~(unsigned int)fkey[row]);  // low 32 bits = ~argmin
    out[t] = embedT[idx * E_DIM + c];
}

extern "C" void kernel_launch(void* const* d_in, const int* in_sizes, int n_in,
                              void* d_out, int out_size, void* d_ws, size_t ws_size,
                              hipStream_t stream) {
    const float* x     = (const float*)d_in[0];
    const float* embed = (const float*)d_in[1];
    float* out = (float*)d_out;

    char* ws = (char*)d_ws;
    float* embedT = (float*)ws;                                  // 2 MB
    float* enorm  = (float*)(ws + (2u << 20));                   // 32 KB
    unsigned long long* fkey =
        (unsigned long long*)(ws + (2u << 20) + (32u << 10));    // 128 KB

    transpose_embed<<<dim3(N_EMBED / 32, E_DIM / 32), dim3(32, 32), 0, stream>>>(embed, embedT);
    compute_enorm<<<N_EMBED / 256, 256, 0, stream>>>(embed, enorm);
    init_keys<<<N_ROWS / 256, 256, 0, stream>>>(fkey);
    qdist<<<NRB * NCHUNK, 256, 0, stream>>>(x, embedT, enorm, fkey);
    gather_out<<<(N_ROWS * E_DIM) / 256, 256, 0, stream>>>(fkey, embedT, out);
}

// Round 4
// 195.649 us; speedup vs baseline: 1.8746x; 1.5695x over previous
//
#include <hip/hip_runtime.h>

// Quantizer via bf16x3-split MFMA GEMM + exact-fp32 recheck of near-ties.
//   x: [16,64,32,32] fp32, embed: [64,8192] fp32
//   out[row][c] = embedT[argmax_j (f_row.e_j - ||e_j||^2/2)][c]
//
// a = a_hi + a_lo (two bf16 splits); f.e ~= hi.hi + hi.lo + lo.hi via
// mfma_f32_16x16x32_bf16, acc initialized with bias = -||e||^2/2.
// Rows whose (best - secondbest) < 1e-2 are rescanned exactly in fp32.
//
// R4 fix: B-fragment second K-half is at byte +64 within the 144B padded
// LDS row (channels 32.. at bytes 64..127); R3 read +128 = the pad. Also
// prep's B side spread over 128 blocks (was 8 blocks x 16 serial tiles).

typedef __attribute__((ext_vector_type(8))) __bf16 bf16x8;
typedef __attribute__((ext_vector_type(4))) float f32x4;
typedef unsigned int u32;
typedef unsigned long long u64;

#define N_ROWS  16384
#define E_DIM   64
#define N_EMBED 8192
#define NCHUNK  8
#define COLS_PER_BLOCK (N_EMBED / NCHUNK)   // 1024
#define ROWS_PER_BLOCK 256
#define N_ROWBLK (N_ROWS / ROWS_PER_BLOCK)  // 64
#define ST_COLS 64
#define N_ST (COLS_PER_BLOCK / ST_COLS)     // 16
#define BROW_B 144                          // 72-bf16 padded row (2-way bank alias = free)
#define BUF_B_L (ST_COLS * BROW_B)          // 9216
#define BUF_BIAS (2 * ST_COLS * BROW_B)     // 18432
#define BUFSZ (BUF_BIAS + ST_COLS * 4)      // 18688
#define MARGIN_THR 1e-2f

// ---- workspace byte offsets (~9.7 MB total)
#define WS_AH   0u
#define WS_AL   (2u << 20)
#define WS_BH   (4u << 20)
#define WS_BL   (5u << 20)
#define WS_ET   (6u << 20)
#define WS_BIAS (8u << 20)
#define WS_PB1  (WS_BIAS + (64u << 10))
#define WS_PI1  (WS_PB1 + (512u << 10))
#define WS_PB2  (WS_PI1 + (512u << 10))
#define WS_FIDX (WS_PB2 + (512u << 10))
#define WS_FLAG (WS_FIDX + (64u << 10))
#define WS_CNT  (WS_FLAG + (64u << 10))

__device__ __forceinline__ u32 f32_key(float s) {
    u32 u = __float_as_uint(s);
    return (u & 0x80000000u) ? ~u : (u | 0x80000000u);
}

// ---- K1: prep. Blocks 0..255: split x -> A_hi/A_lo [row][64] bf16.
//          Blocks 256..383: transpose embed tile -> embedT fp32, B_hi/B_lo, bias.
__global__ __launch_bounds__(256) void prep(
        const float* __restrict__ x, const float* __restrict__ embed, char* ws) {
    __shared__ float tile[64][65];
    __bf16* Ah = (__bf16*)(ws + WS_AH);
    __bf16* Al = (__bf16*)(ws + WS_AL);
    __bf16* Bh = (__bf16*)(ws + WS_BH);
    __bf16* Bl = (__bf16*)(ws + WS_BL);
    float*  eT = (float*)(ws + WS_ET);
    float*  bias = (float*)(ws + WS_BIAS);
    const int t = threadIdx.x;
    const int blk = blockIdx.x;

    if (blk < 256) {
        // A side: image b, 64-pixel tile, all 64 channels
        const int b = blk >> 4, p0 = (blk & 15) * 64;
        {
            const int c = t >> 2, seg = (t & 3) * 16;
            const float* src = x + b * 65536 + c * 1024 + p0 + seg;
#pragma unroll
            for (int i = 0; i < 16; ++i) tile[c][seg + i] = src[i];
        }
        __syncthreads();
        const int p = t >> 2, cq = (t & 3) * 16;
        const long row = b * 1024 + p0 + p;
        bf16x8 vh0, vh1, vl0, vl1;
#pragma unroll
        for (int i = 0; i < 16; ++i) {
            float f = tile[cq + i][p];
            __bf16 h = (__bf16)f;
            __bf16 l = (__bf16)(f - (float)h);
            if (i < 8) { vh0[i] = h; vl0[i] = l; }
            else       { vh1[i - 8] = h; vl1[i - 8] = l; }
        }
        *(bf16x8*)(Ah + row * 64 + cq) = vh0;
        *(bf16x8*)(Ah + row * 64 + cq + 8) = vh1;
        *(bf16x8*)(Al + row * 64 + cq) = vl0;
        *(bf16x8*)(Al + row * 64 + cq + 8) = vl1;
    } else {
        if (blk == 256 && t == 0) *(int*)(ws + WS_CNT) = 0;
        const int jbase = (blk - 256) * 64;
        {
            const int c = t >> 2, seg = (t & 3) * 16;
            const float* src = embed + c * N_EMBED + jbase + seg;
#pragma unroll
            for (int i = 0; i < 16; ++i) tile[c][seg + i] = src[i];
        }
        __syncthreads();
        if (t < 64) {   // bias[j] = -0.5*||e_j||^2
            float s = 0.f;
#pragma unroll
            for (int c = 0; c < 64; ++c) { float v = tile[c][t]; s = fmaf(v, v, s); }
            bias[jbase + t] = -0.5f * s;
        }
        const int jl = t >> 2, cq = (t & 3) * 16;
        const long row = jbase + jl;
        bf16x8 vh0, vh1, vl0, vl1;
#pragma unroll
        for (int i = 0; i < 16; ++i) {
            float f = tile[cq + i][jl];
            eT[row * 64 + cq + i] = f;
            __bf16 h = (__bf16)f;
            __bf16 l = (__bf16)(f - (float)h);
            if (i < 8) { vh0[i] = h; vl0[i] = l; }
            else       { vh1[i - 8] = h; vl1[i - 8] = l; }
        }
        *(bf16x8*)(Bh + row * 64 + cq) = vh0;
        *(bf16x8*)(Bh + row * 64 + cq + 8) = vh1;
        *(bf16x8*)(Bl + row * 64 + cq) = vl0;
        *(bf16x8*)(Bl + row * 64 + cq + 8) = vl1;
    }
}

// ---- K2: MFMA GEMM + running top-2 argmax. 512 blocks, 256 thr, 2 blocks/CU.
__global__ __launch_bounds__(256, 2) void qdist(const char* __restrict__ ws_c, char* ws) {
    __shared__ __align__(16) char smem[2 * BUFSZ];
    const __bf16* Ah = (const __bf16*)(ws_c + WS_AH);
    const __bf16* Al = (const __bf16*)(ws_c + WS_AL);
    const char* BhB = ws_c + WS_BH;
    const char* BlB = ws_c + WS_BL;
    const float* biasg = (const float*)(ws_c + WS_BIAS);
    float* pb1 = (float*)(ws + WS_PB1);
    int*   pi1 = (int*)(ws + WS_PI1);
    float* pb2 = (float*)(ws + WS_PB2);

    const int t = threadIdx.x;
    const int wv = t >> 6, lane = t & 63, ln = lane & 15, q = lane >> 4;
    const int rb = blockIdx.x >> 3, chunk = blockIdx.x & 7;
    const int row0 = rb * ROWS_PER_BLOCK;
    const int col0 = chunk * COLS_PER_BLOCK;

    // A fragments: 4 row-tiles x 2 K-halves x {hi,lo}, resident in VGPRs
    bf16x8 afh[4][2], afl[4][2];
#pragma unroll
    for (int rt = 0; rt < 4; ++rt) {
        long row = row0 + wv * 64 + rt * 16 + ln;
        long base = row * 64 + q * 8;
        afh[rt][0] = *(const bf16x8*)(Ah + base);
        afh[rt][1] = *(const bf16x8*)(Ah + base + 32);
        afl[rt][0] = *(const bf16x8*)(Al + base);
        afl[rt][1] = *(const bf16x8*)(Al + base + 32);
    }

    float b1[16], b2[16]; int i1[16];
#pragma unroll
    for (int k = 0; k < 16; ++k) { b1[k] = -3.4e38f; b2[k] = -3.4e38f; i1[k] = 0; }

    float4 sh0, sh1, sl0, sl1; float sbv = 0.f;
    const int c0 = t >> 3, q0 = (t & 7) * 16;          // lds chunk for t
    const int c1 = (t + 256) >> 3;                     // lds chunk for t+256

    auto issue = [&](int st) {
        const char* ph = BhB + (((size_t)(col0 + st * 64)) << 7);
        const char* pl = BlB + (((size_t)(col0 + st * 64)) << 7);
        sh0 = *(const float4*)(ph + t * 16);
        sh1 = *(const float4*)(ph + (t + 256) * 16);
        sl0 = *(const float4*)(pl + t * 16);
        sl1 = *(const float4*)(pl + (t + 256) * 16);
        if (t < 64) sbv = biasg[col0 + st * 64 + t];
    };
    auto commit = [&](int st) {
        char* bp = smem + (st & 1) * BUFSZ;
        *(float4*)(bp + c0 * BROW_B + q0) = sh0;
        *(float4*)(bp + c1 * BROW_B + q0) = sh1;
        *(float4*)(bp + BUF_B_L + c0 * BROW_B + q0) = sl0;
        *(float4*)(bp + BUF_B_L + c1 * BROW_B + q0) = sl1;
        if (t < 64) *(float*)(bp + BUF_BIAS + t * 4) = sbv;
    };

    issue(0); commit(0); __syncthreads();

    for (int st = 0; st < N_ST; ++st) {
        if (st + 1 < N_ST) issue(st + 1);
        const char* bufp = smem + (st & 1) * BUFSZ;
#pragma unroll
        for (int ct = 0; ct < 4; ++ct) {
            const int cl = ct * 16 + ln;
            const int bo = cl * BROW_B + q * 16;
            // channels q*8..q*8+7 at byte q*16; channels 32+q*8.. at byte 64+q*16
            bf16x8 bh0 = *(const bf16x8*)(bufp + bo);
            bf16x8 bh1 = *(const bf16x8*)(bufp + bo + 64);
            bf16x8 bl0 = *(const bf16x8*)(bufp + BUF_B_L + bo);
            bf16x8 bl1 = *(const bf16x8*)(bufp + BUF_B_L + bo + 64);
            float bv = *(const float*)(bufp + BUF_BIAS + cl * 4);
            int j = col0 + st * 64 + cl;
#pragma unroll
            for (int rt = 0; rt < 4; ++rt) {
                f32x4 acc = {bv, bv, bv, bv};
                acc = __builtin_amdgcn_mfma_f32_16x16x32_bf16(afl[rt][0], bh0, acc, 0, 0, 0);
                acc = __builtin_amdgcn_mfma_f32_16x16x32_bf16(afl[rt][1], bh1, acc, 0, 0, 0);
                acc = __builtin_amdgcn_mfma_f32_16x16x32_bf16(afh[rt][0], bl0, acc, 0, 0, 0);
                acc = __builtin_amdgcn_mfma_f32_16x16x32_bf16(afh[rt][1], bl1, acc, 0, 0, 0);
                acc = __builtin_amdgcn_mfma_f32_16x16x32_bf16(afh[rt][0], bh0, acc, 0, 0, 0);
                acc = __builtin_amdgcn_mfma_f32_16x16x32_bf16(afh[rt][1], bh1, acc, 0, 0, 0);
#pragma unroll
                for (int r = 0; r < 4; ++r) {
                    float s = acc[r];
                    int k = rt * 4 + r;
                    bool better = s > b1[k];
                    b2[k] = fmaxf(fminf(s, b1[k]), b2[k]);   // top-2 update
                    if (better) { b1[k] = s; i1[k] = j; }
                }
            }
        }
        if (st + 1 < N_ST) { commit(st + 1); __syncthreads(); }
    }

    // merge the 16 column-stripe lanes (within each quad) via butterfly
#pragma unroll
    for (int m = 1; m < 16; m <<= 1) {
#pragma unroll
        for (int k = 0; k < 16; ++k) {
            float o1 = __shfl_xor(b1[k], m);
            int   oi = __shfl_xor(i1[k], m);
            float o2 = __shfl_xor(b2[k], m);
            float nb2 = fmaxf(fminf(b1[k], o1), fmaxf(b2[k], o2));
            bool take = (o1 > b1[k]) || (o1 == b1[k] && oi < i1[k]);
            if (take) { b1[k] = o1; i1[k] = oi; }
            b2[k] = nb2;
        }
    }
    if (ln < 4) {
        const int r = ln;
#pragma unroll
        for (int rt = 0; rt < 4; ++rt) {
            int row = row0 + wv * 64 + rt * 16 + q * 4 + r;
            int o = chunk * N_ROWS + row;
            pb1[o] = b1[rt * 4 + r];
            pi1[o] = i1[rt * 4 + r];
            pb2[o] = b2[rt * 4 + r];
        }
    }
}

// ---- K3: merge chunks per row; flag near-ties for exact recheck
__global__ __launch_bounds__(256) void reduce_rows(char* ws) {
    const float* pb1 = (const float*)(ws + WS_PB1);
    const int*   pi1 = (const int*)(ws + WS_PI1);
    const float* pb2 = (const float*)(ws + WS_PB2);
    int* fidx = (int*)(ws + WS_FIDX);
    int* flags = (int*)(ws + WS_FLAG);
    int* cnt = (int*)(ws + WS_CNT);
    const int gid = blockIdx.x * 256 + threadIdx.x;
    float b1 = pb1[gid]; int i1 = pi1[gid]; float b2 = pb2[gid];
#pragma unroll
    for (int ch = 1; ch < NCHUNK; ++ch) {
        float o1 = pb1[ch * N_ROWS + gid];
        int   oi = pi1[ch * N_ROWS + gid];
        float o2 = pb2[ch * N_ROWS + gid];
        float nb2 = fmaxf(fminf(b1, o1), fmaxf(b2, o2));
        if (o1 > b1) { b1 = o1; i1 = oi; }   // equal -> keep earlier (smaller j)
        b2 = nb2;
    }
    fidx[gid] = i1;
    if (b1 - b2 < MARGIN_THR) flags[atomicAdd(cnt, 1)] = gid;
}

// ---- K4: exact fp32 rescan of flagged rows (expected ~hundreds of rows)
__global__ __launch_bounds__(256) void recheck(const float* __restrict__ x, char* ws) {
    __shared__ float fl[64];
    __shared__ u64 red[256];
    const float* eT = (const float*)(ws + WS_ET);
    const float* bias = (const float*)(ws + WS_BIAS);
    const int* flags = (const int*)(ws + WS_FLAG);
    const int n = *(const int*)(ws + WS_CNT);
    int* fidx = (int*)(ws + WS_FIDX);
    const int t = threadIdx.x;
    for (int fi = blockIdx.x; fi < n; fi += gridDim.x) {
        const int row = flags[fi];
        __syncthreads();
        if (t < 64) fl[t] = x[(row >> 10) * 65536 + t * 1024 + (row & 1023)];
        __syncthreads();
        float lb = -3.4e38f; int li = 0;
        for (int j = t; j < N_EMBED; j += 256) {
            const float* e = eT + j * 64;
            float s = bias[j];
#pragma unroll
            for (int c = 0; c < 64; ++c) s = fmaf(fl[c], e[c], s);
            if (s > lb) { lb = s; li = j; }
        }
        red[t] = ((u64)f32_key(lb) << 32) | (u32)(~(u32)li);
        __syncthreads();
        for (int off = 128; off; off >>= 1) {
            if (t < off) { u64 o = red[t + off]; if (o > red[t]) red[t] = o; }
            __syncthreads();
        }
        if (t == 0) fidx[row] = (int)(~(u32)red[0]);
    }
}

// ---- K5: gather winning codes (exact fp32 from embedT)
__global__ __launch_bounds__(256) void gather_out(const char* __restrict__ ws,
                                                  float* __restrict__ out) {
    const int* fidx = (const int*)(ws + WS_FIDX);
    const float* eT = (const float*)(ws + WS_ET);
    int g = blockIdx.x * 256 + threadIdx.x;
    int row = g >> 6, c = g & 63;
    out[g] = eT[fidx[row] * 64 + c];
}

extern "C" void kernel_launch(void* const* d_in, const int* in_sizes, int n_in,
                              void* d_out, int out_size, void* d_ws, size_t ws_size,
                              hipStream_t stream) {
    const float* x     = (const float*)d_in[0];
    const float* embed = (const float*)d_in[1];
    float* out = (float*)d_out;
    char* ws = (char*)d_ws;

    prep<<<384, 256, 0, stream>>>(x, embed, ws);
    qdist<<<N_ROWBLK * NCHUNK, 256, 0, stream>>>(ws, ws);
    reduce_rows<<<N_ROWS / 256, 256, 0, stream>>>(ws);
    recheck<<<128, 256, 0, stream>>>(x, ws);
    gather_out<<<(N_ROWS * 64) / 256, 256, 0, stream>>>(ws, out);
}